// Round 1
// baseline (17222.433 us; speedup 1.0000x reference)
//
#include <hip/hip_runtime.h>
#include <cstdint>
#include <cstddef>

#define B_ 128
#define P_ 196
#define ENC_ 2048
#define A_ 512
#define E_ 512
#define D_ 512
#define V_ 10000
#define L_ 52
#define T_ 51

__device__ __forceinline__ float sigf(float x){ return 1.f/(1.f+expf(-x)); }

// ---------------- sort (stable descending by length) ----------------
__global__ void sort_kernel(const int* __restrict__ cap_len, const int* __restrict__ caps,
                            int* __restrict__ order, int* __restrict__ dec_len,
                            int* __restrict__ caps_sorted,
                            float* __restrict__ out_caps, float* __restrict__ out_declen){
  __shared__ int len_s[B_];
  int i = threadIdx.x;
  len_s[i] = cap_len[i];
  __syncthreads();
  int li = len_s[i];
  int pos = 0;
  for (int j = 0; j < B_; j++){
    int lj = len_s[j];
    pos += (lj > li) || (lj == li && j < i);
  }
  order[pos] = i;
  dec_len[pos] = li - 1;
  out_declen[pos] = (float)(li - 1);
  for (int l = 0; l < L_; l++){
    int v = caps[i * L_ + l];
    caps_sorted[pos * L_ + l] = v;
    out_caps[pos * L_ + l] = (float)v;
  }
}

// ---------------- weight packing + state init ----------------
__global__ void pack_kernel(const float* __restrict__ Wd, const float* __restrict__ bd,
                            const float* __restrict__ Wbeta, const float* __restrict__ bbeta,
                            const float* __restrict__ W_ih, const float* __restrict__ b_ih,
                            const float* __restrict__ W_hh, const float* __restrict__ b_hh,
                            float* __restrict__ Wcat_pre, float* __restrict__ bias_pre,
                            float* __restrict__ Wcat_g, float* __restrict__ bias_g,
                            float* __restrict__ h, float* __restrict__ c, float* __restrict__ xh){
  size_t idx = (size_t)blockIdx.x * blockDim.x + threadIdx.x;
  size_t stride = (size_t)gridDim.x * blockDim.x;
  // Wcat_pre = [Wd (512x512) ; Wbeta (2048x512)] -- flat concat since K matches
  const size_t n_pre = (size_t)2560 * 512;
  for (size_t i = idx; i < n_pre; i += stride)
    Wcat_pre[i] = (i < (size_t)512 * 512) ? Wd[i] : Wbeta[i - (size_t)512 * 512];
  for (size_t i = idx; i < 2560; i += stride)
    bias_pre[i] = (i < 512) ? bd[i] : bbeta[i - 512];
  // Wcat_g rows: [W_ih row (2560) | W_hh row (512)] -> 2048 x 3072
  const size_t n_g = (size_t)2048 * 3072;
  for (size_t i = idx; i < n_g; i += stride){
    size_t j = i / 3072, k = i % 3072;
    Wcat_g[i] = (k < 2560) ? W_ih[j * 2560 + k] : W_hh[j * 512 + (k - 2560)];
  }
  for (size_t i = idx; i < 2048; i += stride) bias_g[i] = b_ih[i] + b_hh[i];
  for (size_t i = idx; i < (size_t)B_ * D_; i += stride){
    h[i] = 0.f; c[i] = 0.f;
    size_t b = i / D_, d = i % D_;
    xh[b * 3072 + 2560 + d] = 0.f;
  }
}

// ---------------- generic fp32 GEMM: C(MxN) = A(MxK) * B(NxK)^T + bias ----------------
// epi_mode: 0 = plain store; 1 = sigmoid for cols >= sig_start; 2 = preds epilogue
// order != nullptr: A row m maps to source row order[m/P_]*P_ + m%P_ (encoder gather)
#define BM 64
#define BN 64
#define BK 16

__launch_bounds__(256)
__global__ void gemm_tn(const float* __restrict__ Ap, int lda,
                        const float* __restrict__ Bp,
                        const float* __restrict__ bias,
                        float* __restrict__ Cp, int ldc,
                        int M, int N, int K,
                        int epi_mode, int sig_start,
                        const int* __restrict__ order,
                        const int* __restrict__ dec_len, float* __restrict__ out_preds)
{
  __shared__ float As[BK][BM + 4];
  __shared__ float Bs[BK][BN + 4];
  int tid = threadIdx.x;
  int m0 = blockIdx.y * BM, n0 = blockIdx.x * BN;
  int lr = tid >> 2;          // 0..63
  int lk = (tid & 3) * 4;     // 0,4,8,12

  int am = m0 + lr;           // always < M for our launches (M % 64 == 0)
  const float* arow;
  if (order){
    int bb = am / P_, pp = am % P_;
    arow = Ap + (size_t)(order[bb] * P_ + pp) * lda;
  } else {
    arow = Ap + (size_t)am * lda;
  }
  int bn = n0 + lr;
  const float* brow = Bp + (size_t)bn * K;
  bool bvalid = (bn < N);

  int tr = tid >> 4, tc = tid & 15;
  float acc[4][4] = {};

  for (int k0 = 0; k0 < K; k0 += BK){
    float4 av = *(const float4*)(arow + k0 + lk);
    As[lk + 0][lr] = av.x; As[lk + 1][lr] = av.y;
    As[lk + 2][lr] = av.z; As[lk + 3][lr] = av.w;
    float4 bv = {0.f, 0.f, 0.f, 0.f};
    if (bvalid) bv = *(const float4*)(brow + k0 + lk);
    Bs[lk + 0][lr] = bv.x; Bs[lk + 1][lr] = bv.y;
    Bs[lk + 2][lr] = bv.z; Bs[lk + 3][lr] = bv.w;
    __syncthreads();
#pragma unroll
    for (int k = 0; k < BK; k++){
      float4 a = *(const float4*)&As[k][tr * 4];
      float4 b = *(const float4*)&Bs[k][tc * 4];
      acc[0][0] += a.x * b.x; acc[0][1] += a.x * b.y; acc[0][2] += a.x * b.z; acc[0][3] += a.x * b.w;
      acc[1][0] += a.y * b.x; acc[1][1] += a.y * b.y; acc[1][2] += a.y * b.z; acc[1][3] += a.y * b.w;
      acc[2][0] += a.z * b.x; acc[2][1] += a.z * b.y; acc[2][2] += a.z * b.z; acc[2][3] += a.z * b.w;
      acc[3][0] += a.w * b.x; acc[3][1] += a.w * b.y; acc[3][2] += a.w * b.z; acc[3][3] += a.w * b.w;
    }
    __syncthreads();
  }

#pragma unroll
  for (int i = 0; i < 4; i++){
#pragma unroll
    for (int j = 0; j < 4; j++){
      int m = m0 + tr * 4 + i, n = n0 + tc * 4 + j;
      if (m < M && n < N){
        float v = acc[i][j] + (bias ? bias[n] : 0.f);
        if (epi_mode == 1 && n >= sig_start) v = sigf(v);
        if (epi_mode == 2){
          int t = m / B_, b = m % B_;
          if (t >= dec_len[b]) v = 0.f;
          out_preds[((size_t)b * T_ + t) * (size_t)V_ + n] = v;
        } else {
          Cp[(size_t)m * ldc + n] = v;
        }
      }
    }
  }
}

// ---------------- attention scores: wf . relu(enc_att[b,p,:] + dec_att[b,:]) + bf ----
__global__ void scores_kernel(const float* __restrict__ enc_att, const float* __restrict__ out_pre,
                              const float* __restrict__ wf, const float* __restrict__ bf,
                              float* __restrict__ scores){
  int wave = blockIdx.x * 4 + (threadIdx.x >> 6);
  int lane = threadIdx.x & 63;
  int b = wave / P_, p = wave % P_;
  const float* ea = enc_att + ((size_t)b * P_ + p) * A_;
  const float* da = out_pre + (size_t)b * 2560;   // dec_att = cols [0,512)
  float s = 0.f;
#pragma unroll
  for (int j = lane; j < A_; j += 64){
    float v = ea[j] + da[j];
    v = fmaxf(v, 0.f);
    s += v * wf[j];
  }
#pragma unroll
  for (int off = 32; off > 0; off >>= 1) s += __shfl_down(s, off);
  if (lane == 0) scores[b * P_ + p] = s + bf[0];
}

// ---------------- softmax + awe + gate mult + emb gather -> xh ----------------
__global__ void awe_kernel(const float* __restrict__ enc, const int* __restrict__ order,
                           const float* __restrict__ scores, const float* __restrict__ out_pre,
                           const float* __restrict__ emb, const int* __restrict__ caps_sorted,
                           float* __restrict__ xh, int t){
  __shared__ float al[P_];
  __shared__ float red[256];
  int b = blockIdx.y, tid = threadIdx.x;
  float sv = (tid < P_) ? scores[b * P_ + tid] : -1e30f;
  red[tid] = sv; __syncthreads();
  for (int s = 128; s > 0; s >>= 1){ if (tid < s) red[tid] = fmaxf(red[tid], red[tid + s]); __syncthreads(); }
  float mx = red[0]; __syncthreads();
  float ex = (tid < P_) ? expf(sv - mx) : 0.f;
  red[tid] = ex; __syncthreads();
  for (int s = 128; s > 0; s >>= 1){ if (tid < s) red[tid] += red[tid + s]; __syncthreads(); }
  float inv = 1.f / red[0];
  if (tid < P_) al[tid] = ex * inv;
  __syncthreads();

  int e4 = (blockIdx.x * 256 + tid) * 4;
  const float* encb = enc + (size_t)order[b] * P_ * ENC_ + e4;
  float4 acc = {0.f, 0.f, 0.f, 0.f};
#pragma unroll 4
  for (int p = 0; p < P_; p++){
    float a = al[p];
    float4 v = *(const float4*)(encb + (size_t)p * ENC_);
    acc.x += a * v.x; acc.y += a * v.y; acc.z += a * v.z; acc.w += a * v.w;
  }
  float4 g = *(const float4*)(out_pre + (size_t)b * 2560 + 512 + e4); // gate (sigmoid applied)
  float4 r; r.x = g.x * acc.x; r.y = g.y * acc.y; r.z = g.z * acc.z; r.w = g.w * acc.w;
  *(float4*)(xh + (size_t)b * 3072 + 512 + e4) = r;

  if (blockIdx.x == 0){
    int tok = caps_sorted[b * L_ + t];
    for (int j = tid; j < E_; j += 256)
      xh[(size_t)b * 3072 + j] = emb[(size_t)tok * E_ + j];
  }
}

// ---------------- LSTM pointwise update ----------------
__global__ void lstm_kernel(const float* __restrict__ gates, float* __restrict__ h, float* __restrict__ c,
                            float* __restrict__ hnew_all, float* __restrict__ xh,
                            const int* __restrict__ dec_len, int t){
  int idx = blockIdx.x * blockDim.x + threadIdx.x;   // < 128*512
  int b = idx >> 9, d = idx & 511;
  const float* gr = gates + (size_t)b * 2048;
  float i_ = gr[d], f_ = gr[512 + d], g_ = gr[1024 + d], o_ = gr[1536 + d];
  float cn = sigf(f_) * c[idx] + sigf(i_) * tanhf(g_);
  float hn = sigf(o_) * tanhf(cn);
  bool act = t < dec_len[b];
  float hv = act ? hn : h[idx];
  float cv = act ? cn : c[idx];
  h[idx] = hv; c[idx] = cv;
  hnew_all[(size_t)t * (B_ * D_) + idx] = hn;
  xh[(size_t)b * 3072 + 2560 + d] = hv;
}

extern "C" void kernel_launch(void* const* d_in, const int* in_sizes, int n_in,
                              void* d_out, int out_size, void* d_ws, size_t ws_size,
                              hipStream_t stream) {
  const float* encoder_out = (const float*)d_in[0];
  const int*   caps        = (const int*)d_in[1];
  const int*   cap_len     = (const int*)d_in[2];
  const float* emb         = (const float*)d_in[3];
  const float* We          = (const float*)d_in[4];
  const float* be          = (const float*)d_in[5];
  const float* Wd          = (const float*)d_in[6];
  const float* bd          = (const float*)d_in[7];
  const float* wf          = (const float*)d_in[8];
  const float* bf          = (const float*)d_in[9];
  const float* W_ih        = (const float*)d_in[10];
  const float* b_ih        = (const float*)d_in[11];
  const float* W_hh        = (const float*)d_in[12];
  const float* b_hh        = (const float*)d_in[13];
  const float* Wbeta       = (const float*)d_in[14];
  const float* bbeta       = (const float*)d_in[15];
  const float* Wfc         = (const float*)d_in[16];
  const float* bfc         = (const float*)d_in[17];

  float* out_preds  = (float*)d_out;
  float* out_caps   = out_preds + (size_t)B_ * T_ * V_;
  float* out_declen = out_caps + (size_t)B_ * L_;

  // ---- workspace carve (256B aligned) ----
  char* w = (char*)d_ws;
  auto alloc = [&](size_t bytes) -> void* {
    void* p = (void*)w;
    w += (bytes + 255) & ~(size_t)255;
    return p;
  };
  int*   order       = (int*)alloc(B_ * 4);
  int*   dec_len     = (int*)alloc(B_ * 4);
  int*   caps_sorted = (int*)alloc((size_t)B_ * L_ * 4);
  float* Wcat_pre    = (float*)alloc((size_t)2560 * 512 * 4);
  float* bias_pre    = (float*)alloc(2560 * 4);
  float* Wcat_g      = (float*)alloc((size_t)2048 * 3072 * 4);
  float* bias_g      = (float*)alloc(2048 * 4);
  float* enc_att     = (float*)alloc((size_t)B_ * P_ * A_ * 4);
  float* out_pre     = (float*)alloc((size_t)B_ * 2560 * 4);
  float* scores      = (float*)alloc((size_t)B_ * P_ * 4);
  float* xh          = (float*)alloc((size_t)B_ * 3072 * 4);
  float* gates       = (float*)alloc((size_t)B_ * 2048 * 4);
  float* h           = (float*)alloc((size_t)B_ * D_ * 4);
  float* c           = (float*)alloc((size_t)B_ * D_ * 4);
  float* hnew_all    = (float*)alloc((size_t)T_ * B_ * D_ * 4);

  // ---- setup ----
  sort_kernel<<<1, 128, 0, stream>>>(cap_len, caps, order, dec_len, caps_sorted, out_caps, out_declen);
  pack_kernel<<<1024, 256, 0, stream>>>(Wd, bd, Wbeta, bbeta, W_ih, b_ih, W_hh, b_hh,
                                        Wcat_pre, bias_pre, Wcat_g, bias_g, h, c, xh);

  // enc_att = enc[order] @ We^T + be : M=25088, N=512, K=2048 (row-gather on A)
  gemm_tn<<<dim3(A_ / BN, (B_ * P_) / BM), 256, 0, stream>>>(
      encoder_out, ENC_, We, be, enc_att, A_,
      B_ * P_, A_, ENC_, 0, 0, order, nullptr, nullptr);

  // ---- time loop ----
  for (int t = 0; t < T_; t++){
    // out_pre = h @ [Wd;Wbeta]^T + [bd;bbeta], sigmoid for cols >= 512
    gemm_tn<<<dim3(2560 / BN, B_ / BM), 256, 0, stream>>>(
        h, D_, Wcat_pre, bias_pre, out_pre, 2560,
        B_, 2560, D_, 1, 512, nullptr, nullptr, nullptr);

    scores_kernel<<<(B_ * P_) / 4, 256, 0, stream>>>(enc_att, out_pre, wf, bf, scores);

    awe_kernel<<<dim3(ENC_ / 1024, B_), 256, 0, stream>>>(
        encoder_out, order, scores, out_pre, emb, caps_sorted, xh, t);

    // gates = xh @ [W_ih|W_hh]^T + (b_ih + b_hh)
    gemm_tn<<<dim3(2048 / BN, B_ / BM), 256, 0, stream>>>(
        xh, 3072, Wcat_g, bias_g, gates, 2048,
        B_, 2048, 3072, 0, 0, nullptr, nullptr, nullptr);

    lstm_kernel<<<(B_ * D_) / 256, 256, 0, stream>>>(gates, h, c, hnew_all, xh, dec_len, t);
  }

  // preds: (T*B, V) = hnew_all @ Wfc^T + bfc, masked + scattered to (B,T,V)
  gemm_tn<<<dim3((V_ + BN - 1) / BN, (T_ * B_) / BM), 256, 0, stream>>>(
      hnew_all, D_, Wfc, bfc, nullptr, 0,
      T_ * B_, V_, D_, 2, 0, nullptr, dec_len, out_preds);
}

// Round 2
// 4173.153 us; speedup vs baseline: 4.1270x; 4.1270x over previous
//
#include <hip/hip_runtime.h>
#include <cstdint>
#include <cstddef>

#define B_ 128
#define P_ 196
#define ENC_ 2048
#define A_ 512
#define E_ 512
#define D_ 512
#define V_ 10000
#define L_ 52
#define T_ 51

using short8 = __attribute__((ext_vector_type(8))) short;
using short4v = __attribute__((ext_vector_type(4))) short;
using floatx4 = __attribute__((ext_vector_type(4))) float;

__device__ __forceinline__ float sigf(float x){ return 1.f/(1.f+expf(-x)); }

__device__ __forceinline__ unsigned short f2bf(float f){
  unsigned int u = __float_as_uint(f);
  unsigned int r = (u + 0x7fffu + ((u >> 16) & 1u)) >> 16;
  return (unsigned short)r;
}
__device__ __forceinline__ float bf2f(unsigned short u){
  return __uint_as_float(((unsigned int)u) << 16);
}

// ---------------- sort (stable descending by length) ----------------
__global__ void sort_kernel(const int* __restrict__ cap_len, const int* __restrict__ caps,
                            int* __restrict__ order, int* __restrict__ dec_len,
                            int* __restrict__ caps_sorted,
                            float* __restrict__ out_caps, float* __restrict__ out_declen){
  __shared__ int len_s[B_];
  int i = threadIdx.x;
  len_s[i] = cap_len[i];
  __syncthreads();
  int li = len_s[i];
  int pos = 0;
  for (int j = 0; j < B_; j++){
    int lj = len_s[j];
    pos += (lj > li) || (lj == li && j < i);
  }
  order[pos] = i;
  dec_len[pos] = li - 1;
  out_declen[pos] = (float)(li - 1);
  for (int l = 0; l < L_; l++){
    int v = caps[i * L_ + l];
    caps_sorted[pos * L_ + l] = v;
    out_caps[pos * L_ + l] = (float)v;
  }
}

// ---------------- enc gather + fp32->bf16 ----------------
// grid (392, 128), 256 thr; 392*256*4 = 401408 = P_*ENC_
__global__ void gather_kernel(const float* __restrict__ enc, const int* __restrict__ order,
                              unsigned short* __restrict__ enc_s){
  int b = blockIdx.y;
  int i = (blockIdx.x * 256 + threadIdx.x) * 4;
  const float4 v = *(const float4*)(enc + (size_t)order[b] * (P_ * ENC_) + i);
  short4v r;
  r[0] = (short)f2bf(v.x); r[1] = (short)f2bf(v.y);
  r[2] = (short)f2bf(v.z); r[3] = (short)f2bf(v.w);
  *(short4v*)(enc_s + (size_t)b * (P_ * ENC_) + i) = r;
}

// ---------------- weight conversion/packing + state init ----------------
__global__ void prep_kernel(const float* __restrict__ We, const float* __restrict__ Wd,
                            const float* __restrict__ Wbeta,
                            const float* __restrict__ W_ih, const float* __restrict__ W_hh,
                            const float* __restrict__ Wfc,
                            const float* __restrict__ bd, const float* __restrict__ bbeta,
                            const float* __restrict__ b_ih, const float* __restrict__ b_hh,
                            unsigned short* __restrict__ We_b, unsigned short* __restrict__ Wpre_b,
                            unsigned short* __restrict__ Wg_b, unsigned short* __restrict__ Wfc_b,
                            float* __restrict__ bias_pre, float* __restrict__ bias_g,
                            float* __restrict__ out_pre,
                            float* __restrict__ h, float* __restrict__ c,
                            unsigned short* __restrict__ h_b, unsigned short* __restrict__ xh){
  unsigned int idx = blockIdx.x * blockDim.x + threadIdx.x;
  unsigned int stride = gridDim.x * blockDim.x;
  // We_b: 512x2048 direct
  for (unsigned int i = idx; i < 512u * 2048u; i += stride) We_b[i] = f2bf(We[i]);
  // Wpre_b = [Wd(512x512) ; Wbeta(2048x512)] flat concat (K matches)
  for (unsigned int i = idx; i < 2560u * 512u; i += stride)
    Wpre_b[i] = f2bf(i < 512u * 512u ? Wd[i] : Wbeta[i - 512u * 512u]);
  // Wg_b rows: [W_ih row(2560) | W_hh row(512)] -> 2048 x 3072
  for (unsigned int i = idx; i < 2048u * 3072u; i += stride){
    unsigned int j = i / 3072u, k = i - j * 3072u;
    Wg_b[i] = f2bf(k < 2560u ? W_ih[j * 2560u + k] : W_hh[j * 512u + (k - 2560u)]);
  }
  // Wfc_b: 10000x512 direct
  for (unsigned int i = idx; i < 10000u * 512u; i += stride) Wfc_b[i] = f2bf(Wfc[i]);
  // biases
  for (unsigned int i = idx; i < 2560u; i += stride) bias_pre[i] = (i < 512u) ? bd[i] : bbeta[i - 512u];
  for (unsigned int i = idx; i < 2048u; i += stride) bias_g[i] = b_ih[i] + b_hh[i];
  // out_pre init (t=0) = bias broadcast
  for (unsigned int i = idx; i < (unsigned)B_ * 2560u; i += stride){
    unsigned int k = i % 2560u;
    out_pre[i] = (k < 512u) ? bd[k] : bbeta[k - 512u];
  }
  // state init
  for (unsigned int i = idx; i < (unsigned)B_ * D_; i += stride){
    h[i] = 0.f; c[i] = 0.f; h_b[i] = 0;
    unsigned int b = i >> 9, d = i & 511u;
    xh[(size_t)b * 3072 + 2560 + d] = 0;
  }
}

// ---------------- bf16 MFMA GEMM: C(MxN) = A(MxK) @ B(NxK)^T ----------------
// 128x128 block tile, 256 threads (4 waves in 2x2 of 64x64), BK=32.
// epi 0: atomicAdd fp32 into Cf (bias pre-initialized by producer) [split-K]
// epi 1: Cb[m,n] = bf16(acc + bias[n])
// epi 2: preds scatter: t=m/128,b=m%128; mask t>=dec_len[b]; Cf[(b*T+t)*V+n]
__launch_bounds__(256)
__global__ void gemm_bf16(const unsigned short* __restrict__ A, int lda,
                          const unsigned short* __restrict__ Bm, int ldb,
                          const float* __restrict__ bias,
                          float* __restrict__ Cf, unsigned short* __restrict__ Cb, int ldc,
                          int N, int ksz,
                          int epi, const int* __restrict__ dec_len)
{
  __shared__ unsigned short As[128 * 32];
  __shared__ unsigned short Bs[128 * 32];
  int tid = threadIdx.x;
  int lane = tid & 63, w = tid >> 6;
  int m0 = blockIdx.y * 128, n0 = blockIdx.x * 128;
  int kb = blockIdx.z * ksz;

  const floatx4 vzero = {0.f, 0.f, 0.f, 0.f};
  floatx4 acc[4][4];
#pragma unroll
  for (int i = 0; i < 4; i++)
#pragma unroll
    for (int j = 0; j < 4; j++) acc[i][j] = vzero;

  int mbase = (w & 1) << 6, nbase = (w >> 1) << 6;
  int fr = lane & 15, fk = (lane >> 4) << 3;

  for (int k0 = kb; k0 < kb + ksz; k0 += 32){
#pragma unroll
    for (int r = 0; r < 2; r++){
      int chunk = r * 256 + tid;
      int row = chunk >> 2, kc = (chunk & 3) << 3;
      short8 av = *(const short8*)(A + (size_t)(m0 + row) * lda + k0 + kc);
      int bn = n0 + row; if (bn >= N) bn = N - 1;
      short8 bv = *(const short8*)(Bm + (size_t)bn * ldb + k0 + kc);
      *(short8*)&As[chunk * 8] = av;
      *(short8*)&Bs[chunk * 8] = bv;
    }
    __syncthreads();
    short8 af[4], bf4[4];
#pragma unroll
    for (int i = 0; i < 4; i++){
      af[i]  = *(const short8*)&As[(mbase + i * 16 + fr) * 32 + fk];
      bf4[i] = *(const short8*)&Bs[(nbase + i * 16 + fr) * 32 + fk];
    }
#pragma unroll
    for (int mi = 0; mi < 4; mi++)
#pragma unroll
      for (int ni = 0; ni < 4; ni++)
        acc[mi][ni] = __builtin_amdgcn_mfma_f32_16x16x32_bf16(af[mi], bf4[ni], acc[mi][ni], 0, 0, 0);
    __syncthreads();
  }

#pragma unroll
  for (int mi = 0; mi < 4; mi++){
#pragma unroll
    for (int ni = 0; ni < 4; ni++){
      floatx4 v = acc[mi][ni];
      int col = n0 + nbase + ni * 16 + (lane & 15);
      int rb = m0 + mbase + mi * 16 + ((lane >> 4) << 2);
      if (epi == 0){
#pragma unroll
        for (int r = 0; r < 4; r++)
          atomicAdd(&Cf[(size_t)(rb + r) * ldc + col], v[r]);
      } else if (epi == 1){
        float bb = bias[col];
#pragma unroll
        for (int r = 0; r < 4; r++)
          Cb[(size_t)(rb + r) * ldc + col] = f2bf(v[r] + bb);
      } else {
        if (col < N){
          float bb = bias[col];
#pragma unroll
          for (int r = 0; r < 4; r++){
            int m = rb + r, t = m >> 7, b = m & 127;
            float x = (t < dec_len[b]) ? v[r] + bb : 0.f;
            Cf[((size_t)b * T_ + t) * V_ + col] = x;
          }
        }
      }
    }
  }
}

// ---------------- attention scores: wf . relu(enc_att[b,p,:] + dec_att[b,:]) + bf ----
__global__ void scores_kernel(const unsigned short* __restrict__ enc_att,
                              const float* __restrict__ out_pre,
                              const float* __restrict__ wf, const float* __restrict__ bf,
                              float* __restrict__ scores){
  int wv = blockIdx.x * 4 + (threadIdx.x >> 6);
  int lane = threadIdx.x & 63;
  int b = wv / P_, p = wv - b * P_;
  const unsigned short* ea = enc_att + ((size_t)b * P_ + p) * A_ + lane * 8;
  const float* da = out_pre + (size_t)b * 2560 + lane * 8;
  const float* wp = wf + lane * 8;
  short8 e = *(const short8*)ea;
  float s = 0.f;
#pragma unroll
  for (int j = 0; j < 8; j++){
    float v = bf2f((unsigned short)e[j]) + da[j];
    v = fmaxf(v, 0.f);
    s += v * wp[j];
  }
#pragma unroll
  for (int off = 32; off > 0; off >>= 1) s += __shfl_down(s, off);
  if (lane == 0) scores[b * P_ + p] = s + bf[0];
}

// ---------------- softmax + awe + gate + emb gather -> xh; init gates=bias ----------------
// grid (2, 128) x 256
__global__ void awe_kernel(const unsigned short* __restrict__ enc_s,
                           const float* __restrict__ scores,
                           const float* __restrict__ out_pre,
                           const float* __restrict__ emb, const int* __restrict__ caps_sorted,
                           unsigned short* __restrict__ xh,
                           float* __restrict__ gates, const float* __restrict__ bias_g,
                           int t){
  __shared__ float al[P_];
  __shared__ float red[256];
  int b = blockIdx.y, tid = threadIdx.x;

  // init gates buffer for this step's split-K GEMM (previous lstm finished reading it)
  int gid = (b * 2 + blockIdx.x) * 256 + tid;
  for (int j = gid; j < B_ * 2048; j += B_ * 2048 / 4) gates[j] = bias_g[j & 2047];

  float sv = (tid < P_) ? scores[b * P_ + tid] : -1e30f;
  red[tid] = sv; __syncthreads();
  for (int s = 128; s > 0; s >>= 1){ if (tid < s) red[tid] = fmaxf(red[tid], red[tid + s]); __syncthreads(); }
  float mx = red[0]; __syncthreads();
  float ex = (tid < P_) ? expf(sv - mx) : 0.f;
  red[tid] = ex; __syncthreads();
  for (int s = 128; s > 0; s >>= 1){ if (tid < s) red[tid] += red[tid + s]; __syncthreads(); }
  float inv = 1.f / red[0];
  if (tid < P_) al[tid] = ex * inv;
  __syncthreads();

  int e0 = (blockIdx.x * 256 + tid) * 4;   // 0..2044
  const unsigned short* encb = enc_s + (size_t)b * (P_ * ENC_) + e0;
  float a0 = 0.f, a1 = 0.f, a2 = 0.f, a3 = 0.f;
#pragma unroll 4
  for (int p = 0; p < P_; p++){
    float a = al[p];
    short4v v = *(const short4v*)(encb + (size_t)p * ENC_);
    a0 += a * bf2f((unsigned short)v[0]);
    a1 += a * bf2f((unsigned short)v[1]);
    a2 += a * bf2f((unsigned short)v[2]);
    a3 += a * bf2f((unsigned short)v[3]);
  }
  float4 g4 = *(const float4*)(out_pre + (size_t)b * 2560 + 512 + e0);
  short4v r;
  r[0] = (short)f2bf(sigf(g4.x) * a0);
  r[1] = (short)f2bf(sigf(g4.y) * a1);
  r[2] = (short)f2bf(sigf(g4.z) * a2);
  r[3] = (short)f2bf(sigf(g4.w) * a3);
  *(short4v*)(xh + (size_t)b * 3072 + 512 + e0) = r;

  if (blockIdx.x == 0){
    int tok = caps_sorted[b * L_ + t];
    for (int j = tid; j < E_; j += 256)
      xh[(size_t)b * 3072 + j] = f2bf(emb[(size_t)tok * E_ + j]);
  }
}

// ---------------- LSTM pointwise; init out_pre=bias for next step ----------------
__global__ void lstm_kernel(const float* __restrict__ gates, float* __restrict__ h, float* __restrict__ c,
                            unsigned short* __restrict__ h_b, unsigned short* __restrict__ xh,
                            unsigned short* __restrict__ hnew_b,
                            float* __restrict__ out_pre, const float* __restrict__ bias_pre,
                            const int* __restrict__ dec_len, int t){
  int idx = blockIdx.x * 256 + threadIdx.x;   // 65536 total
  int b = idx >> 9, d = idx & 511;
  const float* gr = gates + (size_t)b * 2048;
  float i_ = gr[d], f_ = gr[512 + d], g_ = gr[1024 + d], o_ = gr[1536 + d];
  float cn = sigf(f_) * c[idx] + sigf(i_) * tanhf(g_);
  float hn = sigf(o_) * tanhf(cn);
  bool act = t < dec_len[b];
  float hv = act ? hn : h[idx];
  float cv = act ? cn : c[idx];
  h[idx] = hv; c[idx] = cv;
  unsigned short hvb = f2bf(hv);
  h_b[idx] = hvb;
  xh[(size_t)b * 3072 + 2560 + d] = hvb;
  hnew_b[(size_t)t * (B_ * D_) + idx] = f2bf(hn);
  for (int j = idx; j < B_ * 2560; j += B_ * D_) out_pre[j] = bias_pre[j % 2560];
}

extern "C" void kernel_launch(void* const* d_in, const int* in_sizes, int n_in,
                              void* d_out, int out_size, void* d_ws, size_t ws_size,
                              hipStream_t stream) {
  const float* encoder_out = (const float*)d_in[0];
  const int*   caps        = (const int*)d_in[1];
  const int*   cap_len     = (const int*)d_in[2];
  const float* emb         = (const float*)d_in[3];
  const float* We          = (const float*)d_in[4];
  const float* be          = (const float*)d_in[5];
  const float* Wd          = (const float*)d_in[6];
  const float* bd          = (const float*)d_in[7];
  const float* wf          = (const float*)d_in[8];
  const float* bf          = (const float*)d_in[9];
  const float* W_ih        = (const float*)d_in[10];
  const float* b_ih        = (const float*)d_in[11];
  const float* W_hh        = (const float*)d_in[12];
  const float* b_hh        = (const float*)d_in[13];
  const float* Wbeta       = (const float*)d_in[14];
  const float* bbeta       = (const float*)d_in[15];
  const float* Wfc         = (const float*)d_in[16];
  const float* bfc         = (const float*)d_in[17];

  float* out_preds  = (float*)d_out;
  float* out_caps   = out_preds + (size_t)B_ * T_ * V_;
  float* out_declen = out_caps + (size_t)B_ * L_;

  char* w = (char*)d_ws;
  auto alloc = [&](size_t bytes) -> void* {
    void* p = (void*)w;
    w += (bytes + 255) & ~(size_t)255;
    return p;
  };
  int*   order       = (int*)alloc(B_ * 4);
  int*   dec_len     = (int*)alloc(B_ * 4);
  int*   caps_sorted = (int*)alloc((size_t)B_ * L_ * 4);
  unsigned short* enc_s   = (unsigned short*)alloc((size_t)B_ * P_ * ENC_ * 2);
  unsigned short* We_b    = (unsigned short*)alloc((size_t)512 * 2048 * 2);
  unsigned short* Wpre_b  = (unsigned short*)alloc((size_t)2560 * 512 * 2);
  unsigned short* Wg_b    = (unsigned short*)alloc((size_t)2048 * 3072 * 2);
  unsigned short* Wfc_b   = (unsigned short*)alloc((size_t)10000 * 512 * 2);
  unsigned short* enc_att = (unsigned short*)alloc((size_t)B_ * P_ * A_ * 2);
  float* bias_pre    = (float*)alloc(2560 * 4);
  float* bias_g      = (float*)alloc(2048 * 4);
  float* out_pre     = (float*)alloc((size_t)B_ * 2560 * 4);
  float* scores      = (float*)alloc((size_t)B_ * P_ * 4);
  unsigned short* xh = (unsigned short*)alloc((size_t)B_ * 3072 * 2);
  float* gates       = (float*)alloc((size_t)B_ * 2048 * 4);
  float* h           = (float*)alloc((size_t)B_ * D_ * 4);
  float* c           = (float*)alloc((size_t)B_ * D_ * 4);
  unsigned short* h_b = (unsigned short*)alloc((size_t)B_ * D_ * 2);
  unsigned short* hnew_b = (unsigned short*)alloc((size_t)T_ * B_ * D_ * 2);

  sort_kernel<<<1, 128, 0, stream>>>(cap_len, caps, order, dec_len, caps_sorted, out_caps, out_declen);
  gather_kernel<<<dim3(392, 128), 256, 0, stream>>>(encoder_out, order, enc_s);
  prep_kernel<<<2048, 256, 0, stream>>>(We, Wd, Wbeta, W_ih, W_hh, Wfc, bd, bbeta, b_ih, b_hh,
                                        We_b, Wpre_b, Wg_b, Wfc_b, bias_pre, bias_g,
                                        out_pre, h, c, h_b, xh);

  // enc_att = enc_s @ We^T + be -> bf16 : M=25088, N=512, K=2048
  gemm_bf16<<<dim3(4, 196, 1), 256, 0, stream>>>(
      enc_s, ENC_, We_b, ENC_, be, nullptr, enc_att, A_, A_, ENC_, 1, nullptr);

  for (int t = 0; t < T_; t++){
    // out_pre += h @ [Wd;Wbeta]^T  (split-K=4, bias pre-initialized)
    gemm_bf16<<<dim3(20, 1, 4), 256, 0, stream>>>(
        h_b, D_, Wpre_b, D_, nullptr, out_pre, nullptr, 2560, 2560, 128, 0, nullptr);

    scores_kernel<<<(B_ * P_) / 4, 256, 0, stream>>>(enc_att, out_pre, wf, bf, scores);

    awe_kernel<<<dim3(2, B_), 256, 0, stream>>>(enc_s, scores, out_pre, emb, caps_sorted,
                                                xh, gates, bias_g, t);

    // gates += xh @ [W_ih|W_hh]^T  (split-K=4, bias pre-initialized by awe)
    gemm_bf16<<<dim3(16, 1, 4), 256, 0, stream>>>(
        xh, 3072, Wg_b, 3072, nullptr, gates, nullptr, 2048, 2048, 768, 0, nullptr);

    lstm_kernel<<<(B_ * D_) / 256, 256, 0, stream>>>(gates, h, c, h_b, xh, hnew_b,
                                                     out_pre, bias_pre, dec_len, t);
  }

  // preds: (T*B, V) = hnew @ Wfc^T + bfc, masked + scattered to (B,T,V)
  gemm_bf16<<<dim3(79, 51, 1), 256, 0, stream>>>(
      hnew_b, D_, Wfc_b, D_, bfc, out_preds, nullptr, 0, V_, 512, 2, dec_len);
}